// Round 14
// baseline (83.890 us; speedup 1.0000x reference)
//
#include <hip/hip_runtime.h>
#include <hip/hip_bf16.h>
#include <math.h>

#define G 4
#define T 2048
#define H 1024
#define E 8
#define NBUK 2048  // 11-bit radix buckets (key>>53)
#define ZB 2048    // K1 zero-fill blocks (issued FIRST; pure store stream)
#define LGB 2048   // K1 logits blocks (pure load/VALU; no stores before loads)
#define K2B 256    // K2 blocks = 32 (g,e) x 8 slices

typedef float f4 __attribute__((ext_vector_type(4)));
typedef unsigned long long u64;

// ---------------------------------------------------------------------------
// K1: BLOCK-ROLE SPLIT (R13 post-mortem: CDNA vmem retires in-order, so a
// wave's logits loads stall behind its own ~48 zero-stores when both live in
// one block -> zero+logits ADD per wave instead of max(). Separate blocks =
// separate waves = true overlap.) Blocks [0,ZB): zero dispatch half.
// Blocks [ZB,ZB+LGB): logits->u64 keys (fp64 path FROZEN, absmax=0.0
// R2-R13). key = prob_bits<<32 | ~t : unique; desc == top_k order.
// ---------------------------------------------------------------------------
__global__ __launch_bounds__(256) void k1_zero_logits(
    const float* __restrict__ x, const float* __restrict__ W,
    const float* __restrict__ b, u64* __restrict__ keys,
    float* __restrict__ lse2, float* __restrict__ out, unsigned n4d) {
  unsigned bid = blockIdx.x;
  unsigned tid = threadIdx.x;

  if (bid < ZB) {
    f4* outD = (f4*)out;
    f4 z = {0.0f, 0.0f, 0.0f, 0.0f};
    for (unsigned i = bid * 256u + tid; i < n4d; i += ZB * 256u) outD[i] = z;
    return;
  }

  int wave = (int)((bid - ZB) * 4 + (tid >> 6));
  int lane = (int)(tid & 63);
  const float* xr = x + (size_t)wave * H;

  double acc0 = 0, acc1 = 0, acc2 = 0, acc3 = 0;
  double acc4 = 0, acc5 = 0, acc6 = 0, acc7 = 0;
#pragma unroll
  for (int j = 0; j < 4; ++j) {
    int hbase = j * 256 + lane * 4;
    f4 xv = *(const f4*)(xr + hbase);
#pragma unroll
    for (int k = 0; k < 4; ++k) {
      const float* wr = W + (size_t)(hbase + k) * 8;
      f4 w0 = *(const f4*)(wr);
      f4 w1 = *(const f4*)(wr + 4);
      double xd = (double)xv[k];
      acc0 += xd * (double)w0[0];
      acc1 += xd * (double)w0[1];
      acc2 += xd * (double)w0[2];
      acc3 += xd * (double)w0[3];
      acc4 += xd * (double)w1[0];
      acc5 += xd * (double)w1[1];
      acc6 += xd * (double)w1[2];
      acc7 += xd * (double)w1[3];
    }
  }
#pragma unroll
  for (int off = 32; off >= 1; off >>= 1) {
    acc0 += __shfl_xor(acc0, off);
    acc1 += __shfl_xor(acc1, off);
    acc2 += __shfl_xor(acc2, off);
    acc3 += __shfl_xor(acc3, off);
    acc4 += __shfl_xor(acc4, off);
    acc5 += __shfl_xor(acc5, off);
    acc6 += __shfl_xor(acc6, off);
    acc7 += __shfl_xor(acc7, off);
  }
  double l0 = acc0 + (double)b[0], l1 = acc1 + (double)b[1];
  double l2 = acc2 + (double)b[2], l3 = acc3 + (double)b[3];
  double l4 = acc4 + (double)b[4], l5 = acc5 + (double)b[5];
  double l6 = acc6 + (double)b[6], l7 = acc7 + (double)b[7];
  double m = fmax(fmax(fmax(l0, l1), fmax(l2, l3)),
                  fmax(fmax(l4, l5), fmax(l6, l7)));
  double la = (lane & 1) ? l1 : l0;
  double lb = (lane & 1) ? l3 : l2;
  double lc = (lane & 1) ? l5 : l4;
  double ld = (lane & 1) ? l7 : l6;
  double le = (lane & 2) ? lb : la;
  double lf = (lane & 2) ? ld : lc;
  double lsel = (lane & 4) ? lf : le;

  double pe = exp(lsel - m);
  double s = pe;
  s += __shfl_xor(s, 1);
  s += __shfl_xor(s, 2);
  s += __shfl_xor(s, 4);  // bitwise == reference's add tree
  double inv = 1.0 / s;
  float pf = (float)(pe * inv);

  int g = wave >> 11;
  int t = wave & (T - 1);
  if (lane < 8) {
    keys[((size_t)g * 8 + lane) * T + t] =
        ((u64)__float_as_uint(pf) << 32) | (unsigned)(~t);
  }
  if (lane == 0) {
    double lse = m + log(s);
    lse2[wave] = (float)(lse * lse);
  }
}

// ---------------------------------------------------------------------------
// K2 (unchanged from R13, best-so-far): 256 blocks = 32 (g,e) x 8 slices.
// Redundant radix-histogram select per (g,e) (bit-exact R9/R12/R13;
// duplicate ones-writes idempotent), gate kept in LDS, combine slab streamed
// from LDS with mod-free column stepping. Block 0 appends z-loss.
// ---------------------------------------------------------------------------
__global__ __launch_bounds__(1024) void k2_select_combine(
    const u64* __restrict__ keys, const float* __restrict__ lse2,
    float* __restrict__ out, unsigned n4d, int max_cap, int ec) {
  __shared__ int hist[NBUK];
  __shared__ int sA[NBUK];
  __shared__ int sB[NBUK];
  __shared__ int cur[NBUK];
  __shared__ u64 srt[T];
  __shared__ float gLds[1024];
  __shared__ double red[256];

  unsigned bid = blockIdx.x;
  unsigned tid = threadIdx.x;
  unsigned mc = (unsigned)max_cap;
  unsigned mc4 = mc >> 2;
  int ge = (int)(bid >> 3);
  int sl = (int)(bid & 7);

  hist[tid] = 0;
  hist[tid + 1024] = 0;
  if (tid < mc) gLds[tid] = 0.0f;
  __syncthreads();

  const u64* kcol = keys + (size_t)ge * T;
  u64 k0 = kcol[tid];
  u64 k1 = kcol[tid + 1024];
  int b0 = (int)(k0 >> 53);
  int b1 = (int)(k1 >> 53);
  atomicAdd(&hist[b0], 1);
  atomicAdd(&hist[b1], 1);
  __syncthreads();

  sA[tid] = hist[tid];
  sA[tid + 1024] = hist[tid + 1024];
  __syncthreads();
  int* src = sA;
  int* dst = sB;
  for (int s = 1; s < NBUK; s <<= 1) {
    for (int i = (int)tid; i < NBUK; i += 1024) {
      int v = src[i];
      if (i + s < NBUK) v += src[i + s];
      dst[i] = v;
    }
    __syncthreads();
    int* tmp = src;
    src = dst;
    dst = tmp;
  }
  for (int i = (int)tid; i < NBUK; i += 1024) cur[i] = src[i] - hist[i];
  __syncthreads();

  int p0 = atomicAdd(&cur[b0], 1);
  srt[p0] = k0;
  int p1 = atomicAdd(&cur[b1], 1);
  srt[p1] = k1;
  __syncthreads();

  const double factors[8] = {0.5, 0.75, 1.0, 1.0, 1.25, 1.25, 1.5, 1.5};
  int cap = (int)((double)ec * factors[ge & 7]);

  int o0 = src[b0] - hist[b0];
  if (o0 < cap) {
    int end = src[b0];
    int c = 0;
    for (int i = o0; i < end; ++i) c += (int)(srt[i] > k0);
    int r = o0 + c;
    if (r < cap) {
      unsigned t = ~(unsigned)k0;
      gLds[r] = __uint_as_float((unsigned)(k0 >> 32));
      out[((size_t)ge * T + t) * mc + r] = 1.0f;  // idempotent across slices
    }
  }
  int o1 = src[b1] - hist[b1];
  if (o1 < cap) {
    int end = src[b1];
    int c = 0;
    for (int i = o1; i < end; ++i) c += (int)(srt[i] > k1);
    int r = o1 + c;
    if (r < cap) {
      unsigned t = ~(unsigned)k1;
      gLds[r] = __uint_as_float((unsigned)(k1 >> 32));
      out[((size_t)ge * T + t) * mc + r] = 1.0f;
    }
  }
  __syncthreads();  // gLds complete

  // combine slab: rows [sl*256, (sl+1)*256) of this ge; mod-free c4 stepping
  {
    const f4* gl4 = (const f4*)gLds;
    unsigned rows = T / 8;         // 256
    unsigned slabf4 = rows * mc4;  // 24576 for mc=384
    f4* dstC = (f4*)out + n4d + ((size_t)ge * T + (unsigned)sl * rows) * mc4;
    unsigned c4 = tid % mc4;
    unsigned step = 1024u % mc4;
    for (unsigned i = tid; i < slabf4; i += 1024u) {
      dstC[i] = gl4[c4];
      c4 += step;
      if (c4 >= mc4) c4 -= mc4;
    }
  }

  // z-loss (block 0; proven 256-thread shape, bit-identical)
  if (bid == 0) {
    if (tid < 256) {
      double s = 0.0;
      for (int i = (int)tid; i < G * T; i += 256) s += (double)lse2[i];
      red[tid] = s;
    }
    __syncthreads();
    for (int off = 128; off > 0; off >>= 1) {
      if ((int)tid < off) red[tid] += red[tid + off];
      __syncthreads();
    }
    if (tid == 0) {
      size_t ne = (size_t)n4d * 4;
      out[2 * ne] = 0.0f;                                   // auxiliary_loss
      out[2 * ne + 1] = (float)(red[0] / (double)(G * T));  // z_loss
    }
  }
}

extern "C" void kernel_launch(void* const* d_in, const int* in_sizes, int n_in,
                              void* d_out, int out_size, void* d_ws,
                              size_t ws_size, hipStream_t stream) {
  const float* x = (const float*)d_in[0];
  const float* W = (const float*)d_in[1];
  const float* b = (const float*)d_in[2];

  // Derive max_cap from out_size: out = 2*G*E*T*max_cap + 2 scalars.
  long long body = (long long)out_size - 2;
  int max_cap = (int)(body / (2LL * G * E * T));  // 384 for ec=256
  if (max_cap <= 0) return;
  int ec = (2 * max_cap) / 3;  // max factor is 1.5

  u64* keys = (u64*)d_ws;                            // 32*2048 u64 = 512 KB
  float* lse2 = (float*)(keys + (size_t)G * E * T);  // 8192 floats

  unsigned n4d = (unsigned)((long long)G * E * T * max_cap / 4);  // per array

  k1_zero_logits<<<ZB + LGB, 256, 0, stream>>>(x, W, b, keys, lse2,
                                               (float*)d_out, n4d);
  k2_select_combine<<<K2B, 1024, 0, stream>>>(keys, lse2, (float*)d_out, n4d,
                                              max_cap, ec);
}

// Round 15
// 82.538 us; speedup vs baseline: 1.0164x; 1.0164x over previous
//
#include <hip/hip_runtime.h>
#include <hip/hip_bf16.h>
#include <math.h>

#define G 4
#define T 2048
#define H 1024
#define E 8
#define NBUK 2048  // 11-bit radix buckets (key>>53)
#define K1B 2048   // K1 logits blocks (4 token-waves each)
#define K2B 256    // K2 blocks = 32 (g,e) x 8 slices

typedef float f4 __attribute__((ext_vector_type(4)));
typedef unsigned long long u64;

// ---------------------------------------------------------------------------
// K1: logits+softmax -> u64 keys ONLY (R15: dispatch zeroing moved into K2's
// dense slab writes — no zero pass at all). fp64 path FROZEN (absmax=0.0
// R2-R14). key = prob_bits<<32 | ~t : unique; desc == (value desc, idx asc).
// ---------------------------------------------------------------------------
__global__ __launch_bounds__(256) void k1_logits(
    const float* __restrict__ x, const float* __restrict__ W,
    const float* __restrict__ b, u64* __restrict__ keys,
    float* __restrict__ lse2) {
  int wave = (int)(blockIdx.x * 4 + (threadIdx.x >> 6));
  int lane = (int)(threadIdx.x & 63);
  const float* xr = x + (size_t)wave * H;

  double acc0 = 0, acc1 = 0, acc2 = 0, acc3 = 0;
  double acc4 = 0, acc5 = 0, acc6 = 0, acc7 = 0;
#pragma unroll
  for (int j = 0; j < 4; ++j) {
    int hbase = j * 256 + lane * 4;
    f4 xv = *(const f4*)(xr + hbase);
#pragma unroll
    for (int k = 0; k < 4; ++k) {
      const float* wr = W + (size_t)(hbase + k) * 8;
      f4 w0 = *(const f4*)(wr);
      f4 w1 = *(const f4*)(wr + 4);
      double xd = (double)xv[k];
      acc0 += xd * (double)w0[0];
      acc1 += xd * (double)w0[1];
      acc2 += xd * (double)w0[2];
      acc3 += xd * (double)w0[3];
      acc4 += xd * (double)w1[0];
      acc5 += xd * (double)w1[1];
      acc6 += xd * (double)w1[2];
      acc7 += xd * (double)w1[3];
    }
  }
#pragma unroll
  for (int off = 32; off >= 1; off >>= 1) {
    acc0 += __shfl_xor(acc0, off);
    acc1 += __shfl_xor(acc1, off);
    acc2 += __shfl_xor(acc2, off);
    acc3 += __shfl_xor(acc3, off);
    acc4 += __shfl_xor(acc4, off);
    acc5 += __shfl_xor(acc5, off);
    acc6 += __shfl_xor(acc6, off);
    acc7 += __shfl_xor(acc7, off);
  }
  double l0 = acc0 + (double)b[0], l1 = acc1 + (double)b[1];
  double l2 = acc2 + (double)b[2], l3 = acc3 + (double)b[3];
  double l4 = acc4 + (double)b[4], l5 = acc5 + (double)b[5];
  double l6 = acc6 + (double)b[6], l7 = acc7 + (double)b[7];
  double m = fmax(fmax(fmax(l0, l1), fmax(l2, l3)),
                  fmax(fmax(l4, l5), fmax(l6, l7)));
  double la = (lane & 1) ? l1 : l0;
  double lb = (lane & 1) ? l3 : l2;
  double lc = (lane & 1) ? l5 : l4;
  double ld = (lane & 1) ? l7 : l6;
  double le = (lane & 2) ? lb : la;
  double lf = (lane & 2) ? ld : lc;
  double lsel = (lane & 4) ? lf : le;

  double pe = exp(lsel - m);
  double s = pe;
  s += __shfl_xor(s, 1);
  s += __shfl_xor(s, 2);
  s += __shfl_xor(s, 4);  // bitwise == reference's add tree
  double inv = 1.0 / s;
  float pf = (float)(pe * inv);

  int g = wave >> 11;
  int t = wave & (T - 1);
  if (lane < 8) {
    keys[((size_t)g * 8 + lane) * T + t] =
        ((u64)__float_as_uint(pf) << 32) | (unsigned)(~t);
  }
  if (lane == 0) {
    double lse = m + log(s);
    lse2[wave] = (float)(lse * lse);
  }
}

// ---------------------------------------------------------------------------
// K2: 256 blocks = 32 (g,e) x 8 slices. Redundant radix select per (g,e)
// (bit-exact R9-R14); every token's rank -> rankLds; then each block DENSELY
// writes its 256-row dispatch slab (zeros + inline 1.0s, branchless static
// f4 lanes) and its combine slab from the LDS gate row. ALL 201MB of output
// leaves as pure coalesced streams written exactly once; no zero pass, no
// scatter, no idempotent double-writes. Block 0 appends z-loss.
// ---------------------------------------------------------------------------
template <int MC4S>
__global__ __launch_bounds__(1024) void k2_select_write(
    const u64* __restrict__ keys, const float* __restrict__ lse2,
    float* __restrict__ out, unsigned n4d, int max_cap, int ec,
    unsigned mc4_rt) {
  __shared__ int hist[NBUK];
  __shared__ int sA[NBUK];
  __shared__ int sB[NBUK];
  __shared__ int cur[NBUK];
  __shared__ u64 srt[T];
  __shared__ float gLds[1024];
  __shared__ int rankLds[T];
  __shared__ double red[256];

  const unsigned mc4 = MC4S ? (unsigned)MC4S : mc4_rt;
  unsigned bid = blockIdx.x;
  unsigned tid = threadIdx.x;
  unsigned mc = (unsigned)max_cap;
  int ge = (int)(bid >> 3);
  int sl = (int)(bid & 7);

  hist[tid] = 0;
  hist[tid + 1024] = 0;
  if (tid < mc) gLds[tid] = 0.0f;
  __syncthreads();

  const u64* kcol = keys + (size_t)ge * T;
  u64 k0 = kcol[tid];
  u64 k1 = kcol[tid + 1024];
  int b0 = (int)(k0 >> 53);
  int b1 = (int)(k1 >> 53);
  atomicAdd(&hist[b0], 1);
  atomicAdd(&hist[b1], 1);
  __syncthreads();

  sA[tid] = hist[tid];
  sA[tid + 1024] = hist[tid + 1024];
  __syncthreads();
  int* src = sA;
  int* dst = sB;
  for (int s = 1; s < NBUK; s <<= 1) {
    for (int i = (int)tid; i < NBUK; i += 1024) {
      int v = src[i];
      if (i + s < NBUK) v += src[i + s];
      dst[i] = v;
    }
    __syncthreads();
    int* tmp = src;
    src = dst;
    dst = tmp;
  }
  for (int i = (int)tid; i < NBUK; i += 1024) cur[i] = src[i] - hist[i];
  __syncthreads();

  int p0 = atomicAdd(&cur[b0], 1);
  srt[p0] = k0;
  int p1 = atomicAdd(&cur[b1], 1);
  srt[p1] = k1;
  __syncthreads();

  const double factors[8] = {0.5, 0.75, 1.0, 1.0, 1.25, 1.25, 1.5, 1.5};
  int cap = (int)((double)ec * factors[ge & 7]);

  // exact rank for my 2 tokens (same math as R9-R14); -1 if not selected
  int rk0 = -1, rk1 = -1;
  int o0 = src[b0] - hist[b0];
  if (o0 < cap) {
    int end = src[b0];
    int c = 0;
    for (int i = o0; i < end; ++i) c += (int)(srt[i] > k0);
    int r = o0 + c;
    if (r < cap) {
      rk0 = r;
      gLds[r] = __uint_as_float((unsigned)(k0 >> 32));
    }
  }
  int o1 = src[b1] - hist[b1];
  if (o1 < cap) {
    int end = src[b1];
    int c = 0;
    for (int i = o1; i < end; ++i) c += (int)(srt[i] > k1);
    int r = o1 + c;
    if (r < cap) {
      rk1 = r;
      gLds[r] = __uint_as_float((unsigned)(k1 >> 32));
    }
  }
  rankLds[tid] = rk0;
  rankLds[tid + 1024] = rk1;
  __syncthreads();  // gLds + rankLds complete

  unsigned rows = T / 8;         // 256 rows per slice
  unsigned slabf4 = rows * mc4;  // 24576 f4 for mc=384

  // dispatch slab: rows [sl*256,(sl+1)*256) of this ge, dense, write-once
  {
    f4* dstD = (f4*)out + ((size_t)ge * T + (unsigned)sl * rows) * mc4;
    for (unsigned i = tid; i < slabf4; i += 1024u) {
      unsigned row = i / mc4;          // magic-mul when MC4S!=0
      unsigned c4 = i - row * mc4;
      int r = rankLds[sl * (int)rows + (int)row];  // LDS broadcast per row
      int base = (int)(c4 * 4);
      f4 dv;
      dv.x = (r == base) ? 1.0f : 0.0f;
      dv.y = (r == base + 1) ? 1.0f : 0.0f;
      dv.z = (r == base + 2) ? 1.0f : 0.0f;
      dv.w = (r == base + 3) ? 1.0f : 0.0f;
      dstD[i] = dv;
    }
  }

  // combine slab: same rows; gate broadcast from LDS, mod-free stepping
  {
    const f4* gl4 = (const f4*)gLds;
    f4* dstC = (f4*)out + n4d + ((size_t)ge * T + (unsigned)sl * rows) * mc4;
    unsigned c4 = tid % mc4;
    unsigned step = 1024u % mc4;
    for (unsigned i = tid; i < slabf4; i += 1024u) {
      dstC[i] = gl4[c4];
      c4 += step;
      if (c4 >= mc4) c4 -= mc4;
    }
  }

  // z-loss (block 0; proven 256-thread shape, bit-identical)
  if (bid == 0) {
    if (tid < 256) {
      double s = 0.0;
      for (int i = (int)tid; i < G * T; i += 256) s += (double)lse2[i];
      red[tid] = s;
    }
    __syncthreads();
    for (int off = 128; off > 0; off >>= 1) {
      if ((int)tid < off) red[tid] += red[tid + off];
      __syncthreads();
    }
    if (tid == 0) {
      size_t ne = (size_t)n4d * 4;
      out[2 * ne] = 0.0f;                                   // auxiliary_loss
      out[2 * ne + 1] = (float)(red[0] / (double)(G * T));  // z_loss
    }
  }
}

extern "C" void kernel_launch(void* const* d_in, const int* in_sizes, int n_in,
                              void* d_out, int out_size, void* d_ws,
                              size_t ws_size, hipStream_t stream) {
  const float* x = (const float*)d_in[0];
  const float* W = (const float*)d_in[1];
  const float* b = (const float*)d_in[2];

  // Derive max_cap from out_size: out = 2*G*E*T*max_cap + 2 scalars.
  long long body = (long long)out_size - 2;
  int max_cap = (int)(body / (2LL * G * E * T));  // 384 for ec=256
  if (max_cap <= 0) return;
  int ec = (2 * max_cap) / 3;  // max factor is 1.5

  u64* keys = (u64*)d_ws;                            // 32*2048 u64 = 512 KB
  float* lse2 = (float*)(keys + (size_t)G * E * T);  // 8192 floats

  unsigned n4d = (unsigned)((long long)G * E * T * max_cap / 4);  // per array

  k1_logits<<<K1B, 256, 0, stream>>>(x, W, b, keys, lse2);
  if (max_cap == 384) {
    k2_select_write<96><<<K2B, 1024, 0, stream>>>(keys, lse2, (float*)d_out,
                                                  n4d, max_cap, ec, 96u);
  } else {
    k2_select_write<0><<<K2B, 1024, 0, stream>>>(
        keys, lse2, (float*)d_out, n4d, max_cap, ec, (unsigned)(max_cap / 4));
  }
}

// Round 16
// 80.098 us; speedup vs baseline: 1.0473x; 1.0305x over previous
//
#include <hip/hip_runtime.h>
#include <hip/hip_bf16.h>
#include <math.h>

#define G 4
#define T 2048
#define H 1024
#define E 8
#define NBUK 2048  // 11-bit radix buckets (key>>53)
#define K1B 2048   // K1 blocks: fused zero-stripe + logits (R13 proven)
#define K3B 2048   // K3 blocks: combine fill, fast store shape

typedef float f4 __attribute__((ext_vector_type(4)));
typedef unsigned long long u64;

// ---------------------------------------------------------------------------
// K1 (R13 verbatim, best-so-far): every block zero-fills its interleaved
// stripe of the dispatch half (4KB/iter granularity -> channels/XCDs spread)
// then computes logits->u64 keys for its 4 tokens. fp64 path FROZEN
// (absmax=0.0 R2-R15). key = prob_bits<<32 | ~t.
// ---------------------------------------------------------------------------
__global__ __launch_bounds__(256) void k1_zero_logits(
    const float* __restrict__ x, const float* __restrict__ W,
    const float* __restrict__ b, u64* __restrict__ keys,
    float* __restrict__ lse2, float* __restrict__ out, unsigned n4d) {
  unsigned bid = blockIdx.x;
  unsigned tid = threadIdx.x;

  {
    f4* outD = (f4*)out;
    f4 z = {0.0f, 0.0f, 0.0f, 0.0f};
    for (unsigned i = bid * 256u + tid; i < n4d; i += K1B * 256u) outD[i] = z;
  }

  int wave = (int)(bid * 4 + (tid >> 6));
  int lane = (int)(tid & 63);
  const float* xr = x + (size_t)wave * H;

  double acc0 = 0, acc1 = 0, acc2 = 0, acc3 = 0;
  double acc4 = 0, acc5 = 0, acc6 = 0, acc7 = 0;
#pragma unroll
  for (int j = 0; j < 4; ++j) {
    int hbase = j * 256 + lane * 4;
    f4 xv = *(const f4*)(xr + hbase);
#pragma unroll
    for (int k = 0; k < 4; ++k) {
      const float* wr = W + (size_t)(hbase + k) * 8;
      f4 w0 = *(const f4*)(wr);
      f4 w1 = *(const f4*)(wr + 4);
      double xd = (double)xv[k];
      acc0 += xd * (double)w0[0];
      acc1 += xd * (double)w0[1];
      acc2 += xd * (double)w0[2];
      acc3 += xd * (double)w0[3];
      acc4 += xd * (double)w1[0];
      acc5 += xd * (double)w1[1];
      acc6 += xd * (double)w1[2];
      acc7 += xd * (double)w1[3];
    }
  }
#pragma unroll
  for (int off = 32; off >= 1; off >>= 1) {
    acc0 += __shfl_xor(acc0, off);
    acc1 += __shfl_xor(acc1, off);
    acc2 += __shfl_xor(acc2, off);
    acc3 += __shfl_xor(acc3, off);
    acc4 += __shfl_xor(acc4, off);
    acc5 += __shfl_xor(acc5, off);
    acc6 += __shfl_xor(acc6, off);
    acc7 += __shfl_xor(acc7, off);
  }
  double l0 = acc0 + (double)b[0], l1 = acc1 + (double)b[1];
  double l2 = acc2 + (double)b[2], l3 = acc3 + (double)b[3];
  double l4 = acc4 + (double)b[4], l5 = acc5 + (double)b[5];
  double l6 = acc6 + (double)b[6], l7 = acc7 + (double)b[7];
  double m = fmax(fmax(fmax(l0, l1), fmax(l2, l3)),
                  fmax(fmax(l4, l5), fmax(l6, l7)));
  double la = (lane & 1) ? l1 : l0;
  double lb = (lane & 1) ? l3 : l2;
  double lc = (lane & 1) ? l5 : l4;
  double ld = (lane & 1) ? l7 : l6;
  double le = (lane & 2) ? lb : la;
  double lf = (lane & 2) ? ld : lc;
  double lsel = (lane & 4) ? lf : le;

  double pe = exp(lsel - m);
  double s = pe;
  s += __shfl_xor(s, 1);
  s += __shfl_xor(s, 2);
  s += __shfl_xor(s, 4);  // bitwise == reference's add tree
  double inv = 1.0 / s;
  float pf = (float)(pe * inv);

  int g = wave >> 11;
  int t = wave & (T - 1);
  if (lane < 8) {
    keys[((size_t)g * 8 + lane) * T + t] =
        ((u64)__float_as_uint(pf) << 32) | (unsigned)(~t);
  }
  if (lane == 0) {
    double lse = m + log(s);
    lse2[wave] = (float)(lse * lse);
  }
}

// ---------------------------------------------------------------------------
// K2: 32 blocks x 1024 — radix-histogram select ONLY (bit-exact R9-R15).
// One block per (g,e): writes gate row to ws (pad slots zeroed) and the cap
// winners' 1.0s into the pre-zeroed dispatch half. Short serial stage; no
// bulk stores here (R15 lesson: big-block slab stores run at ~2.5-3 TB/s).
// ---------------------------------------------------------------------------
__global__ __launch_bounds__(1024) void k2_select(
    const u64* __restrict__ keys, float* __restrict__ gate,
    float* __restrict__ out, int max_cap, int ec) {
  __shared__ int hist[NBUK];
  __shared__ int sA[NBUK];
  __shared__ int sB[NBUK];
  __shared__ int cur[NBUK];
  __shared__ u64 srt[T];

  unsigned tid = threadIdx.x;
  unsigned mc = (unsigned)max_cap;
  int ge = (int)blockIdx.x;

  hist[tid] = 0;
  hist[tid + 1024] = 0;
  if (tid < mc) gate[(size_t)ge * mc + tid] = 0.0f;
  __syncthreads();

  const u64* kcol = keys + (size_t)ge * T;
  u64 k0 = kcol[tid];
  u64 k1 = kcol[tid + 1024];
  int b0 = (int)(k0 >> 53);
  int b1 = (int)(k1 >> 53);
  atomicAdd(&hist[b0], 1);
  atomicAdd(&hist[b1], 1);
  __syncthreads();

  sA[tid] = hist[tid];
  sA[tid + 1024] = hist[tid + 1024];
  __syncthreads();
  int* src = sA;
  int* dst = sB;
  for (int s = 1; s < NBUK; s <<= 1) {
    for (int i = (int)tid; i < NBUK; i += 1024) {
      int v = src[i];
      if (i + s < NBUK) v += src[i + s];
      dst[i] = v;
    }
    __syncthreads();
    int* tmp = src;
    src = dst;
    dst = tmp;
  }
  for (int i = (int)tid; i < NBUK; i += 1024) cur[i] = src[i] - hist[i];
  __syncthreads();

  int p0 = atomicAdd(&cur[b0], 1);
  srt[p0] = k0;
  int p1 = atomicAdd(&cur[b1], 1);
  srt[p1] = k1;
  __syncthreads();

  const double factors[8] = {0.5, 0.75, 1.0, 1.0, 1.25, 1.25, 1.5, 1.5};
  int cap = (int)((double)ec * factors[ge & 7]);

  int o0 = src[b0] - hist[b0];
  if (o0 < cap) {
    int end = src[b0];
    int c = 0;
    for (int i = o0; i < end; ++i) c += (int)(srt[i] > k0);
    int r = o0 + c;
    if (r < cap) {
      unsigned t = ~(unsigned)k0;
      gate[(size_t)ge * mc + r] = __uint_as_float((unsigned)(k0 >> 32));
      out[((size_t)ge * T + t) * mc + r] = 1.0f;
    }
  }
  int o1 = src[b1] - hist[b1];
  if (o1 < cap) {
    int end = src[b1];
    int c = 0;
    for (int i = o1; i < end; ++i) c += (int)(srt[i] > k1);
    int r = o1 + c;
    if (r < cap) {
      unsigned t = ~(unsigned)k1;
      gate[(size_t)ge * mc + r] = __uint_as_float((unsigned)(k1 >> 32));
      out[((size_t)ge * T + t) * mc + r] = 1.0f;
    }
  }
}

// ---------------------------------------------------------------------------
// K3: combine fill in the FAST store shape (2048 x 256, interleaved
// grid-stride; gate is 48KB -> L1/L2-resident broadcast). Block 0 = z-loss
// (proven 256-thread shape, bit-identical).
// ---------------------------------------------------------------------------
template <int MC4S>
__global__ __launch_bounds__(256) void k3_combine(
    const float* __restrict__ gate, const float* __restrict__ lse2,
    float* __restrict__ out, unsigned n4d, unsigned mc4_rt) {
  const unsigned mc4 = MC4S ? (unsigned)MC4S : mc4_rt;
  unsigned tid = threadIdx.x;
  unsigned bid = blockIdx.x;

  if (bid == 0) {
    __shared__ double red[256];
    double s = 0.0;
    for (int i = (int)tid; i < G * T; i += 256) s += (double)lse2[i];
    red[tid] = s;
    __syncthreads();
    for (int off = 128; off > 0; off >>= 1) {
      if ((int)tid < off) red[tid] += red[tid + off];
      __syncthreads();
    }
    if (tid == 0) {
      size_t ne = (size_t)n4d * 4;
      out[2 * ne] = 0.0f;                                   // auxiliary_loss
      out[2 * ne + 1] = (float)(red[0] / (double)(G * T));  // z_loss
    }
    return;
  }

  f4* outC = (f4*)out + n4d;
  const f4* gate4 = (const f4*)gate;
  unsigned fb = bid - 1;
  unsigned stride = (K3B - 1) * 256u;
  for (unsigned i = fb * 256u + tid; i < n4d; i += stride) {
    unsigned row = i / mc4;  // magic-mul when templated
    unsigned c4 = i - row * mc4;
    unsigned ge = row >> 11;
    outC[i] = gate4[ge * mc4 + c4];
  }
}

extern "C" void kernel_launch(void* const* d_in, const int* in_sizes, int n_in,
                              void* d_out, int out_size, void* d_ws,
                              size_t ws_size, hipStream_t stream) {
  const float* x = (const float*)d_in[0];
  const float* W = (const float*)d_in[1];
  const float* b = (const float*)d_in[2];

  // Derive max_cap from out_size: out = 2*G*E*T*max_cap + 2 scalars.
  long long body = (long long)out_size - 2;
  int max_cap = (int)(body / (2LL * G * E * T));  // 384 for ec=256
  if (max_cap <= 0) return;
  int ec = (2 * max_cap) / 3;  // max factor is 1.5

  u64* keys = (u64*)d_ws;                            // 32*2048 u64 = 512 KB
  float* lse2 = (float*)(keys + (size_t)G * E * T);  // 8192 floats
  float* gate = lse2 + (size_t)G * T;                // G*E*max_cap floats

  unsigned n4d = (unsigned)((long long)G * E * T * max_cap / 4);  // per array

  k1_zero_logits<<<K1B, 256, 0, stream>>>(x, W, b, keys, lse2, (float*)d_out,
                                          n4d);
  k2_select<<<G * E, 1024, 0, stream>>>(keys, gate, (float*)d_out, max_cap,
                                        ec);
  if (max_cap == 384) {
    k3_combine<96><<<K3B, 256, 0, stream>>>(gate, lse2, (float*)d_out, n4d,
                                            96u);
  } else {
    k3_combine<0><<<K3B, 256, 0, stream>>>(gate, lse2, (float*)d_out, n4d,
                                           (unsigned)(max_cap / 4));
  }
}

// Round 17
// 77.599 us; speedup vs baseline: 1.0811x; 1.0322x over previous
//
#include <hip/hip_runtime.h>
#include <hip/hip_bf16.h>
#include <math.h>

#define G 4
#define T 2048
#define H 1024
#define E 8
#define NBUK 2048  // 11-bit radix buckets (key>>53)
#define K1B 2048   // K1 blocks (4 token-waves each)
#define K2B 256    // K2 blocks = 32 (g,e) x 8 slices

typedef float f4 __attribute__((ext_vector_type(4)));
typedef unsigned long long u64;

// ---------------------------------------------------------------------------
// R17 = R13 (best, 73.9us) + NONTEMPORAL stores on the two 100MB write-once
// streams (never A/B'd before; mechanism: keep the 201MB output from
// allocating/dirtying L2 so reads keep the cache and no writeback storm).
// Everything else byte-identical to R13.
//
// K1: every block zero-fills its interleaved stripe of the dispatch half
// (nt stores) then computes logits->u64 keys for its 4 tokens. fp64 path
// FROZEN (absmax=0.0 R2-R16). key = prob_bits<<32 | ~t.
// ---------------------------------------------------------------------------
__global__ __launch_bounds__(256) void k1_zero_logits(
    const float* __restrict__ x, const float* __restrict__ W,
    const float* __restrict__ b, u64* __restrict__ keys,
    float* __restrict__ lse2, float* __restrict__ out, unsigned n4d) {
  unsigned bid = blockIdx.x;
  unsigned tid = threadIdx.x;

  {
    f4* outD = (f4*)out;
    f4 z = {0.0f, 0.0f, 0.0f, 0.0f};
    for (unsigned i = bid * 256u + tid; i < n4d; i += K1B * 256u)
      __builtin_nontemporal_store(z, &outD[i]);
  }

  int wave = (int)(bid * 4 + (tid >> 6));
  int lane = (int)(tid & 63);
  const float* xr = x + (size_t)wave * H;

  double acc0 = 0, acc1 = 0, acc2 = 0, acc3 = 0;
  double acc4 = 0, acc5 = 0, acc6 = 0, acc7 = 0;
#pragma unroll
  for (int j = 0; j < 4; ++j) {
    int hbase = j * 256 + lane * 4;
    f4 xv = *(const f4*)(xr + hbase);
#pragma unroll
    for (int k = 0; k < 4; ++k) {
      const float* wr = W + (size_t)(hbase + k) * 8;
      f4 w0 = *(const f4*)(wr);
      f4 w1 = *(const f4*)(wr + 4);
      double xd = (double)xv[k];
      acc0 += xd * (double)w0[0];
      acc1 += xd * (double)w0[1];
      acc2 += xd * (double)w0[2];
      acc3 += xd * (double)w0[3];
      acc4 += xd * (double)w1[0];
      acc5 += xd * (double)w1[1];
      acc6 += xd * (double)w1[2];
      acc7 += xd * (double)w1[3];
    }
  }
#pragma unroll
  for (int off = 32; off >= 1; off >>= 1) {
    acc0 += __shfl_xor(acc0, off);
    acc1 += __shfl_xor(acc1, off);
    acc2 += __shfl_xor(acc2, off);
    acc3 += __shfl_xor(acc3, off);
    acc4 += __shfl_xor(acc4, off);
    acc5 += __shfl_xor(acc5, off);
    acc6 += __shfl_xor(acc6, off);
    acc7 += __shfl_xor(acc7, off);
  }
  double l0 = acc0 + (double)b[0], l1 = acc1 + (double)b[1];
  double l2 = acc2 + (double)b[2], l3 = acc3 + (double)b[3];
  double l4 = acc4 + (double)b[4], l5 = acc5 + (double)b[5];
  double l6 = acc6 + (double)b[6], l7 = acc7 + (double)b[7];
  double m = fmax(fmax(fmax(l0, l1), fmax(l2, l3)),
                  fmax(fmax(l4, l5), fmax(l6, l7)));
  double la = (lane & 1) ? l1 : l0;
  double lb = (lane & 1) ? l3 : l2;
  double lc = (lane & 1) ? l5 : l4;
  double ld = (lane & 1) ? l7 : l6;
  double le = (lane & 2) ? lb : la;
  double lf = (lane & 2) ? ld : lc;
  double lsel = (lane & 4) ? lf : le;

  double pe = exp(lsel - m);
  double s = pe;
  s += __shfl_xor(s, 1);
  s += __shfl_xor(s, 2);
  s += __shfl_xor(s, 4);  // bitwise == reference's add tree
  double inv = 1.0 / s;
  float pf = (float)(pe * inv);

  int g = wave >> 11;
  int t = wave & (T - 1);
  if (lane < 8) {
    keys[((size_t)g * 8 + lane) * T + t] =
        ((u64)__float_as_uint(pf) << 32) | (unsigned)(~t);
  }
  if (lane == 0) {
    double lse = m + log(s);
    lse2[wave] = (float)(lse * lse);
  }
}

// ---------------------------------------------------------------------------
// K2 (R13 verbatim + nt on combine slab): 256 blocks = 32 (g,e) x 8 slices.
// Redundant radix-histogram select per (g,e) (bit-exact R9-R16; duplicate
// ones-writes idempotent), gate kept in LDS, combine slab streamed from LDS
// with mod-free column stepping. Block 0 appends z-loss.
// ---------------------------------------------------------------------------
__global__ __launch_bounds__(1024) void k2_select_combine(
    const u64* __restrict__ keys, const float* __restrict__ lse2,
    float* __restrict__ out, unsigned n4d, int max_cap, int ec) {
  __shared__ int hist[NBUK];
  __shared__ int sA[NBUK];
  __shared__ int sB[NBUK];
  __shared__ int cur[NBUK];
  __shared__ u64 srt[T];
  __shared__ float gLds[1024];
  __shared__ double red[256];

  unsigned bid = blockIdx.x;
  unsigned tid = threadIdx.x;
  unsigned mc = (unsigned)max_cap;
  unsigned mc4 = mc >> 2;
  int ge = (int)(bid >> 3);
  int sl = (int)(bid & 7);

  hist[tid] = 0;
  hist[tid + 1024] = 0;
  if (tid < mc) gLds[tid] = 0.0f;
  __syncthreads();

  const u64* kcol = keys + (size_t)ge * T;
  u64 k0 = kcol[tid];
  u64 k1 = kcol[tid + 1024];
  int b0 = (int)(k0 >> 53);
  int b1 = (int)(k1 >> 53);
  atomicAdd(&hist[b0], 1);
  atomicAdd(&hist[b1], 1);
  __syncthreads();

  sA[tid] = hist[tid];
  sA[tid + 1024] = hist[tid + 1024];
  __syncthreads();
  int* src = sA;
  int* dst = sB;
  for (int s = 1; s < NBUK; s <<= 1) {
    for (int i = (int)tid; i < NBUK; i += 1024) {
      int v = src[i];
      if (i + s < NBUK) v += src[i + s];
      dst[i] = v;
    }
    __syncthreads();
    int* tmp = src;
    src = dst;
    dst = tmp;
  }
  for (int i = (int)tid; i < NBUK; i += 1024) cur[i] = src[i] - hist[i];
  __syncthreads();

  int p0 = atomicAdd(&cur[b0], 1);
  srt[p0] = k0;
  int p1 = atomicAdd(&cur[b1], 1);
  srt[p1] = k1;
  __syncthreads();

  const double factors[8] = {0.5, 0.75, 1.0, 1.0, 1.25, 1.25, 1.5, 1.5};
  int cap = (int)((double)ec * factors[ge & 7]);

  int o0 = src[b0] - hist[b0];
  if (o0 < cap) {
    int end = src[b0];
    int c = 0;
    for (int i = o0; i < end; ++i) c += (int)(srt[i] > k0);
    int r = o0 + c;
    if (r < cap) {
      unsigned t = ~(unsigned)k0;
      gLds[r] = __uint_as_float((unsigned)(k0 >> 32));
      out[((size_t)ge * T + t) * mc + r] = 1.0f;  // idempotent across slices
    }
  }
  int o1 = src[b1] - hist[b1];
  if (o1 < cap) {
    int end = src[b1];
    int c = 0;
    for (int i = o1; i < end; ++i) c += (int)(srt[i] > k1);
    int r = o1 + c;
    if (r < cap) {
      unsigned t = ~(unsigned)k1;
      gLds[r] = __uint_as_float((unsigned)(k1 >> 32));
      out[((size_t)ge * T + t) * mc + r] = 1.0f;
    }
  }
  __syncthreads();  // gLds complete

  // combine slab: rows [sl*256, (sl+1)*256) of this ge; mod-free c4 stepping
  {
    const f4* gl4 = (const f4*)gLds;
    unsigned rows = T / 8;         // 256
    unsigned slabf4 = rows * mc4;  // 24576 for mc=384
    f4* dstC = (f4*)out + n4d + ((size_t)ge * T + (unsigned)sl * rows) * mc4;
    unsigned c4 = tid % mc4;
    unsigned step = 1024u % mc4;
    for (unsigned i = tid; i < slabf4; i += 1024u) {
      __builtin_nontemporal_store(gl4[c4], &dstC[i]);
      c4 += step;
      if (c4 >= mc4) c4 -= mc4;
    }
  }

  // z-loss (block 0; proven 256-thread shape, bit-identical)
  if (bid == 0) {
    if (tid < 256) {
      double s = 0.0;
      for (int i = (int)tid; i < G * T; i += 256) s += (double)lse2[i];
      red[tid] = s;
    }
    __syncthreads();
    for (int off = 128; off > 0; off >>= 1) {
      if ((int)tid < off) red[tid] += red[tid + off];
      __syncthreads();
    }
    if (tid == 0) {
      size_t ne = (size_t)n4d * 4;
      out[2 * ne] = 0.0f;                                   // auxiliary_loss
      out[2 * ne + 1] = (float)(red[0] / (double)(G * T));  // z_loss
    }
  }
}

extern "C" void kernel_launch(void* const* d_in, const int* in_sizes, int n_in,
                              void* d_out, int out_size, void* d_ws,
                              size_t ws_size, hipStream_t stream) {
  const float* x = (const float*)d_in[0];
  const float* W = (const float*)d_in[1];
  const float* b = (const float*)d_in[2];

  // Derive max_cap from out_size: out = 2*G*E*T*max_cap + 2 scalars.
  long long body = (long long)out_size - 2;
  int max_cap = (int)(body / (2LL * G * E * T));  // 384 for ec=256
  if (max_cap <= 0) return;
  int ec = (2 * max_cap) / 3;  // max factor is 1.5

  u64* keys = (u64*)d_ws;                            // 32*2048 u64 = 512 KB
  float* lse2 = (float*)(keys + (size_t)G * E * T);  // 8192 floats

  unsigned n4d = (unsigned)((long long)G * E * T * max_cap / 4);  // per array

  k1_zero_logits<<<K1B, 256, 0, stream>>>(x, W, b, keys, lse2, (float*)d_out,
                                          n4d);
  k2_select_combine<<<K2B, 1024, 0, stream>>>(keys, lse2, (float*)d_out, n4d,
                                              max_cap, ec);
}

// Round 18
// 73.211 us; speedup vs baseline: 1.1459x; 1.0599x over previous
//
#include <hip/hip_runtime.h>
#include <hip/hip_bf16.h>
#include <math.h>

#define G 4
#define T 2048
#define H 1024
#define E 8
#define NBUK 2048  // 11-bit radix buckets (key>>53)
#define K1B 2048   // K1 blocks (4 token-waves each)
#define K2B 256    // K2 blocks = 32 (g,e) x 8 slices

typedef float f4 __attribute__((ext_vector_type(4)));
typedef unsigned long long u64;

// ---------------------------------------------------------------------------
// R18 = R13 (best, 73.9us; nt reverted — R17 A/B showed neutral/negative)
// with ONE change in K2's combine loop: stride = multiple of mc4 so each
// thread's column is loop-invariant -> gate value hoisted to a register ->
// the 100MB combine stream becomes a LOAD-FREE pure-store loop (the pattern
// that runs at ~6TB/s in K1's zero-fill and the harness memset), instead of
// a dependent LDS read before every 16B store. Plus: dispatch-ones written
// by slice 0 only (was 8x redundant). All numerics byte-identical.
//
// K1 (R13 verbatim): zero-stripe dispatch half + logits->u64 keys. fp64 path
// FROZEN (absmax=0.0 R2-R17). key = prob_bits<<32 | ~t.
// ---------------------------------------------------------------------------
__global__ __launch_bounds__(256) void k1_zero_logits(
    const float* __restrict__ x, const float* __restrict__ W,
    const float* __restrict__ b, u64* __restrict__ keys,
    float* __restrict__ lse2, float* __restrict__ out, unsigned n4d) {
  unsigned bid = blockIdx.x;
  unsigned tid = threadIdx.x;

  {
    f4* outD = (f4*)out;
    f4 z = {0.0f, 0.0f, 0.0f, 0.0f};
    for (unsigned i = bid * 256u + tid; i < n4d; i += K1B * 256u) outD[i] = z;
  }

  int wave = (int)(bid * 4 + (tid >> 6));
  int lane = (int)(tid & 63);
  const float* xr = x + (size_t)wave * H;

  double acc0 = 0, acc1 = 0, acc2 = 0, acc3 = 0;
  double acc4 = 0, acc5 = 0, acc6 = 0, acc7 = 0;
#pragma unroll
  for (int j = 0; j < 4; ++j) {
    int hbase = j * 256 + lane * 4;
    f4 xv = *(const f4*)(xr + hbase);
#pragma unroll
    for (int k = 0; k < 4; ++k) {
      const float* wr = W + (size_t)(hbase + k) * 8;
      f4 w0 = *(const f4*)(wr);
      f4 w1 = *(const f4*)(wr + 4);
      double xd = (double)xv[k];
      acc0 += xd * (double)w0[0];
      acc1 += xd * (double)w0[1];
      acc2 += xd * (double)w0[2];
      acc3 += xd * (double)w0[3];
      acc4 += xd * (double)w1[0];
      acc5 += xd * (double)w1[1];
      acc6 += xd * (double)w1[2];
      acc7 += xd * (double)w1[3];
    }
  }
#pragma unroll
  for (int off = 32; off >= 1; off >>= 1) {
    acc0 += __shfl_xor(acc0, off);
    acc1 += __shfl_xor(acc1, off);
    acc2 += __shfl_xor(acc2, off);
    acc3 += __shfl_xor(acc3, off);
    acc4 += __shfl_xor(acc4, off);
    acc5 += __shfl_xor(acc5, off);
    acc6 += __shfl_xor(acc6, off);
    acc7 += __shfl_xor(acc7, off);
  }
  double l0 = acc0 + (double)b[0], l1 = acc1 + (double)b[1];
  double l2 = acc2 + (double)b[2], l3 = acc3 + (double)b[3];
  double l4 = acc4 + (double)b[4], l5 = acc5 + (double)b[5];
  double l6 = acc6 + (double)b[6], l7 = acc7 + (double)b[7];
  double m = fmax(fmax(fmax(l0, l1), fmax(l2, l3)),
                  fmax(fmax(l4, l5), fmax(l6, l7)));
  double la = (lane & 1) ? l1 : l0;
  double lb = (lane & 1) ? l3 : l2;
  double lc = (lane & 1) ? l5 : l4;
  double ld = (lane & 1) ? l7 : l6;
  double le = (lane & 2) ? lb : la;
  double lf = (lane & 2) ? ld : lc;
  double lsel = (lane & 4) ? lf : le;

  double pe = exp(lsel - m);
  double s = pe;
  s += __shfl_xor(s, 1);
  s += __shfl_xor(s, 2);
  s += __shfl_xor(s, 4);  // bitwise == reference's add tree
  double inv = 1.0 / s;
  float pf = (float)(pe * inv);

  int g = wave >> 11;
  int t = wave & (T - 1);
  if (lane < 8) {
    keys[((size_t)g * 8 + lane) * T + t] =
        ((u64)__float_as_uint(pf) << 32) | (unsigned)(~t);
  }
  if (lane == 0) {
    double lse = m + log(s);
    lse2[wave] = (float)(lse * lse);
  }
}

// ---------------------------------------------------------------------------
// K2: 256 blocks = 32 (g,e) x 8 slices. Redundant radix select per (g,e)
// (bit-exact R9-R17), gate in LDS; ones written by slice 0 only; combine
// slab written as a LOAD-FREE register-sourced store stream (stride = 
// rowspan*mc4 so column is thread-invariant). Block 0 appends z-loss.
// ---------------------------------------------------------------------------
__global__ __launch_bounds__(1024) void k2_select_combine(
    const u64* __restrict__ keys, const float* __restrict__ lse2,
    float* __restrict__ out, unsigned n4d, int max_cap, int ec) {
  __shared__ int hist[NBUK];
  __shared__ int sA[NBUK];
  __shared__ int sB[NBUK];
  __shared__ int cur[NBUK];
  __shared__ u64 srt[T];
  __shared__ float gLds[1024];
  __shared__ double red[256];

  unsigned bid = blockIdx.x;
  unsigned tid = threadIdx.x;
  unsigned mc = (unsigned)max_cap;
  unsigned mc4 = mc >> 2;
  int ge = (int)(bid >> 3);
  int sl = (int)(bid & 7);

  hist[tid] = 0;
  hist[tid + 1024] = 0;
  if (tid < mc) gLds[tid] = 0.0f;
  __syncthreads();

  const u64* kcol = keys + (size_t)ge * T;
  u64 k0 = kcol[tid];
  u64 k1 = kcol[tid + 1024];
  int b0 = (int)(k0 >> 53);
  int b1 = (int)(k1 >> 53);
  atomicAdd(&hist[b0], 1);
  atomicAdd(&hist[b1], 1);
  __syncthreads();

  sA[tid] = hist[tid];
  sA[tid + 1024] = hist[tid + 1024];
  __syncthreads();
  int* src = sA;
  int* dst = sB;
  for (int s = 1; s < NBUK; s <<= 1) {
    for (int i = (int)tid; i < NBUK; i += 1024) {
      int v = src[i];
      if (i + s < NBUK) v += src[i + s];
      dst[i] = v;
    }
    __syncthreads();
    int* tmp = src;
    src = dst;
    dst = tmp;
  }
  for (int i = (int)tid; i < NBUK; i += 1024) cur[i] = src[i] - hist[i];
  __syncthreads();

  int p0 = atomicAdd(&cur[b0], 1);
  srt[p0] = k0;
  int p1 = atomicAdd(&cur[b1], 1);
  srt[p1] = k1;
  __syncthreads();

  const double factors[8] = {0.5, 0.75, 1.0, 1.0, 1.25, 1.25, 1.5, 1.5};
  int cap = (int)((double)ec * factors[ge & 7]);

  int o0 = src[b0] - hist[b0];
  if (o0 < cap) {
    int end = src[b0];
    int c = 0;
    for (int i = o0; i < end; ++i) c += (int)(srt[i] > k0);
    int r = o0 + c;
    if (r < cap) {
      unsigned t = ~(unsigned)k0;
      gLds[r] = __uint_as_float((unsigned)(k0 >> 32));
      if (sl == 0) out[((size_t)ge * T + t) * mc + r] = 1.0f;
    }
  }
  int o1 = src[b1] - hist[b1];
  if (o1 < cap) {
    int end = src[b1];
    int c = 0;
    for (int i = o1; i < end; ++i) c += (int)(srt[i] > k1);
    int r = o1 + c;
    if (r < cap) {
      unsigned t = ~(unsigned)k1;
      gLds[r] = __uint_as_float((unsigned)(k1 >> 32));
      if (sl == 0) out[((size_t)ge * T + t) * mc + r] = 1.0f;
    }
  }
  __syncthreads();  // gLds complete

  // combine slab: rows [sl*256,(sl+1)*256) of this ge. Stride = rowspan*mc4
  // (960 for mc4=96) -> off % mc4 == tid % mc4 invariant -> gate value
  // hoisted to a register; loop body = pure contiguous f4 stores.
  {
    unsigned rows = T / 8;               // 256
    unsigned slabf4 = rows * mc4;        // 24576 for mc=384
    unsigned rowspan = 1024u / mc4;      // 10
    unsigned active = rowspan * mc4;     // 960
    f4* dstC = (f4*)out + n4d + ((size_t)ge * T + (unsigned)sl * rows) * mc4;
    if (tid < active) {
      f4 gv = ((const f4*)gLds)[tid % mc4];  // one LDS read, then store-only
      for (unsigned off = tid; off < slabf4; off += active) dstC[off] = gv;
    }
  }

  // z-loss (block 0; proven 256-thread shape, bit-identical)
  if (bid == 0) {
    if (tid < 256) {
      double s = 0.0;
      for (int i = (int)tid; i < G * T; i += 256) s += (double)lse2[i];
      red[tid] = s;
    }
    __syncthreads();
    for (int off = 128; off > 0; off >>= 1) {
      if ((int)tid < off) red[tid] += red[tid + off];
      __syncthreads();
    }
    if (tid == 0) {
      size_t ne = (size_t)n4d * 4;
      out[2 * ne] = 0.0f;                                   // auxiliary_loss
      out[2 * ne + 1] = (float)(red[0] / (double)(G * T));  // z_loss
    }
  }
}

extern "C" void kernel_launch(void* const* d_in, const int* in_sizes, int n_in,
                              void* d_out, int out_size, void* d_ws,
                              size_t ws_size, hipStream_t stream) {
  const float* x = (const float*)d_in[0];
  const float* W = (const float*)d_in[1];
  const float* b = (const float*)d_in[2];

  // Derive max_cap from out_size: out = 2*G*E*T*max_cap + 2 scalars.
  long long body = (long long)out_size - 2;
  int max_cap = (int)(body / (2LL * G * E * T));  // 384 for ec=256
  if (max_cap <= 0) return;
  int ec = (2 * max_cap) / 3;  // max factor is 1.5

  u64* keys = (u64*)d_ws;                            // 32*2048 u64 = 512 KB
  float* lse2 = (float*)(keys + (size_t)G * E * T);  // 8192 floats

  unsigned n4d = (unsigned)((long long)G * E * T * max_cap / 4);  // per array

  k1_zero_logits<<<K1B, 256, 0, stream>>>(x, W, b, keys, lse2, (float*)d_out,
                                          n4d);
  k2_select_combine<<<K2B, 1024, 0, stream>>>(keys, lse2, (float*)d_out, n4d,
                                              max_cap, ec);
}